// Round 16
// baseline (1635.603 us; speedup 1.0000x reference)
//
#include <hip/hip_runtime.h>
#include <stdint.h>
#include <math.h>

#define B_ 64
#define S_ 512
#define I_ 128
#define H_ 2048
#define O_ 128
#define NWG 256            /* 4 quarters x 64 WGs; 16 rows x 32 cols each */
#define COLS 32
#define NTHREADS 256
#define SLAB (B_ * H_)      /* 131072 elements per h snapshot */
#define QTR_ 32768          /* elements per quarter-slab (16 rows x 2048) */
#define RSTR 36             /* sRed row stride in floats (32 + 4 pad) */
#define SENTW 0x7FC07FC0u   /* qNaN|qNaN — tanh output always has bit14=0 */
#define SENTMASK 0x40004000u
#define DELAY_BURN 104      /* r26: 144->104 (~420cy); FETCH is the guard */

typedef __attribute__((ext_vector_type(8))) __bf16 bf16x8;
typedef __attribute__((ext_vector_type(4))) float floatx4;
typedef __attribute__((ext_vector_type(2))) float floatx2;
typedef __attribute__((ext_vector_type(4))) unsigned int uintx4;

__device__ __forceinline__ unsigned short f2bf(float f) {
    unsigned u = __float_as_uint(f);
    unsigned r = u + 0x7fffu + ((u >> 16) & 1u);   // RNE
    return (unsigned short)(r >> 16);
}
__device__ __forceinline__ float bf2f(unsigned short h) {
    return __uint_as_float(((unsigned)h) << 16);
}
// tanh(x) = 1 - 2/(e^{2x}+1); err ~1e-6 << bf16 noise.
__device__ __forceinline__ float fast_tanh(float x) {
    float e = __expf(2.0f * x);
    return 1.0f - 2.0f * __builtin_amdgcn_rcpf(e + 1.0f);
}

// VALU work overlapping in-flight VMEM / absorbing publish flight.
__device__ __forceinline__ void burn(int n) {
    float a = 1.0f, b = 1.0f;
    const float c = 1.0000001f, d = 0.9999999f;
    for (int i = 0; i < n; ++i)
        asm volatile("v_fmac_f32 %0, %2, %2\n\tv_fmac_f32 %1, %3, %3"
                     : "+v"(a), "+v"(b) : "v"(c), "v"(d));
}

// sc0 sc1 b128 load (bypass L1/L2 -> MALL truth). r19 lesson: NO cached
// h loads — a pre-arrival line cached in L2 serves stale sentinel forever.
// r22 lesson: NO probes — the speculative data read IS the detector.
#define LDG0(dst, addr) \
    asm volatile("global_load_dwordx4 %0, %1, off sc0 sc1" \
                 : "=v"(dst) : "v"(addr))

// one chunk's 4 MFMAs (hi+lo x two 16-col tiles)
__device__ __forceinline__ void mfma_chunk(
    floatx4& a00, floatx4& a01, const uintx4 gk,
    const uintx4 whAk, const uintx4 wlAk,
    const uintx4 whBk, const uintx4 wlBk)
{
    const bf16x8 h0 = __builtin_bit_cast(bf16x8, gk);
    const bf16x8 hA = __builtin_bit_cast(bf16x8, whAk);
    const bf16x8 lA = __builtin_bit_cast(bf16x8, wlAk);
    const bf16x8 hB = __builtin_bit_cast(bf16x8, whBk);
    const bf16x8 lB = __builtin_bit_cast(bf16x8, wlBk);
    a00 = __builtin_amdgcn_mfma_f32_16x16x32_bf16(h0, hA, a00, 0, 0, 0);
    a01 = __builtin_amdgcn_mfma_f32_16x16x32_bf16(h0, hB, a01, 0, 0, 0);
    a00 = __builtin_amdgcn_mfma_f32_16x16x32_bf16(h0, lA, a00, 0, 0, 0);
    a01 = __builtin_amdgcn_mfma_f32_16x16x32_bf16(h0, lB, a01, 0, 0, 0);
}

// ---- prep kernels -------------------------------------------------------
__global__ void k_wsplit(const float* __restrict__ whh, const float* __restrict__ mask,
                         unsigned short* __restrict__ hi, unsigned short* __restrict__ lo, int n) {
    int i = blockIdx.x * blockDim.x + threadIdx.x;
    int stride = gridDim.x * blockDim.x;
    for (; i < n; i += stride) {
        float w = whh[i] * mask[i];
        unsigned short h = f2bf(w);
        hi[i] = h;
        lo[i] = f2bf(w - bf2f(h));
    }
}
__global__ void k_split(const float* __restrict__ src,
                        unsigned short* __restrict__ hi, unsigned short* __restrict__ lo, int n) {
    int i = blockIdx.x * blockDim.x + threadIdx.x;
    int stride = gridDim.x * blockDim.x;
    for (; i < n; i += stride) {
        float w = src[i];
        unsigned short h = f2bf(w);
        hi[i] = h;
        lo[i] = f2bf(w - bf2f(h));
    }
}
__global__ void k_cast(const float* __restrict__ src, unsigned short* __restrict__ dst, int n) {
    int i = blockIdx.x * blockDim.x + threadIdx.x;
    int stride = gridDim.x * blockDim.x;
    for (; i < n; i += stride) dst[i] = f2bf(src[i]);
}
// fill hs slabs 1..512 with sentinel (sc1 write-through: no dirty copies)
__global__ void k_sent(uintx4* __restrict__ p, int n4) {
    int i = blockIdx.x * blockDim.x + threadIdx.x;
    int stride = gridDim.x * blockDim.x;
    uintx4 s = {SENTW, SENTW, SENTW, SENTW};
    for (; i < n4; i += stride)
        asm volatile("global_store_dwordx4 %0, %1, off sc1"
                     :: "v"(p + i), "v"(s) : "memory");
}

// ---- persistent recurrence kernel --------------------------------------
// Round-26: r25 + DELAY MICRO-TUNE (144->104) + drop post-issue burn.
//  r25 state: 4-stage split-wait (vmcnt 12/8/4/0), group validation
//  (1 ballot / 4 chunks), per-chunk retry backstop, tuned pre-issue
//  delay. FETCH pinned at 567MB for 3 rounds => retries ~0 => the delay
//  may be over-provisioned. Reclaim ~160cy/step; FETCH is the tripwire
//  (retry inflation shows immediately). If flat/regressed: structure is
//  at its serial-chain + MALL-service floor (~5.9 TB/s broadcast).
__global__ __attribute__((amdgpu_flat_work_group_size(NTHREADS, NTHREADS),
                          amdgpu_waves_per_eu(1, 1))) void k_rnn(
    const unsigned short* __restrict__ whi, const unsigned short* __restrict__ wlo,
    const unsigned short* __restrict__ wihh, const unsigned short* __restrict__ wihl,
    const unsigned short* __restrict__ xbf, const float* __restrict__ bih,
    unsigned short* hs)
{
    __shared__ float sRed[2][4 * 16 * RSTR];
    __shared__ float sBih[COLS];

    const int tid   = threadIdx.x;
    const int wg    = blockIdx.x;
    const int qt    = wg >> 6;          // quarter: rows qt*16..qt*16+15
    const int wgl   = wg & 63;
    const int j0    = wgl * COLS;
    const int rbase = qt * 16;
    const int w     = tid >> 6;
    const int lane  = tid & 63;
    const int q     = lane >> 4;
    const int nn    = lane & 15;
    const int kb    = w * 512;   // this wave's k range in H
    const int xkb   = w * 32;    // this wave's k range in I

    if (tid < COLS) sBih[tid] = bih[j0 + tid];

    // W fragments — loaded once, laundered opaque (stay resident).
    uintx4 whA[16], wlA[16], whB[16], wlB[16];
    uintx4 bxhA_u, bxlA_u, bxhB_u, bxlB_u;
    {
        const size_t wrowA = (size_t)(j0 + nn)      * H_ + (size_t)(kb + q * 8);
        const size_t wrowB = (size_t)(j0 + 16 + nn) * H_ + (size_t)(kb + q * 8);
#pragma unroll
        for (int ks = 0; ks < 16; ++ks) {
            whA[ks] = *(const uintx4*)&whi[wrowA + ks * 32];
            wlA[ks] = *(const uintx4*)&wlo[wrowA + ks * 32];
            whB[ks] = *(const uintx4*)&whi[wrowB + ks * 32];
            wlB[ks] = *(const uintx4*)&wlo[wrowB + ks * 32];
        }
        const size_t xrowA = (size_t)(j0 + nn)      * I_ + (size_t)(xkb + q * 8);
        const size_t xrowB = (size_t)(j0 + 16 + nn) * I_ + (size_t)(xkb + q * 8);
        bxhA_u = *(const uintx4*)&wihh[xrowA];
        bxlA_u = *(const uintx4*)&wihl[xrowA];
        bxhB_u = *(const uintx4*)&wihh[xrowB];
        bxlB_u = *(const uintx4*)&wihl[xrowB];
#pragma unroll
        for (int ks = 0; ks < 16; ++ks)
            asm volatile("" : "+v"(whA[ks]), "+v"(wlA[ks]),
                              "+v"(whB[ks]), "+v"(wlB[ks]));
        asm volatile("" : "+v"(bxhA_u), "+v"(bxlA_u),
                          "+v"(bxhB_u), "+v"(bxlB_u));
    }
    const bf16x8 bxhA = __builtin_bit_cast(bf16x8, bxhA_u);
    const bf16x8 bxlA = __builtin_bit_cast(bf16x8, bxlA_u);
    const bf16x8 bxhB = __builtin_bit_cast(bf16x8, bxhB_u);
    const bf16x8 bxlB = __builtin_bit_cast(bf16x8, bxlB_u);

    // consumer base: wave w reads blocks w*16+ks of quarter qt
    const unsigned short* const cwbase =
        hs + (size_t)qt * QTR_ + (size_t)w * 8192 + (size_t)lane * 8;

    // producer publish offset: block wgl of quarter qt; 256 threads,
    // row m=tid>>4 (0..15), col pair n0=(tid&15)*2.
    const int m  = tid >> 4;
    const int n0 = (tid & 15) * 2;
    const size_t pub_off =
        (size_t)qt * QTR_ + (size_t)wgl * 512 +
        (size_t)(((n0 >> 3) & 3) * 16 + m) * 8 + (size_t)(n0 & 7);

    // x row for this WG's single 16-row tile
    const unsigned short* const xr0 = xbf + (size_t)(rbase + nn) * (S_ * I_);

    // prologue: prefetch x operand for t=0
    uintx4 xc0;
    {
        xc0 = *(const uintx4*)&xr0[(size_t)xkb + q * 8];
        asm volatile("" : "+v"(xc0));
    }

#pragma unroll 1
    for (int t = 0; t < S_; ++t) {
        const unsigned short* cb = cwbase + (size_t)t * SLAB;

        // (1) register-only x-projection (free delay, no memory)
        floatx4 a00 = {0.f, 0.f, 0.f, 0.f}, a01 = a00;
        {
            bf16x8 x0 = __builtin_bit_cast(bf16x8, xc0);
            a00 = __builtin_amdgcn_mfma_f32_16x16x32_bf16(x0, bxhA, a00, 0, 0, 0);
            a01 = __builtin_amdgcn_mfma_f32_16x16x32_bf16(x0, bxhB, a01, 0, 0, 0);
            a00 = __builtin_amdgcn_mfma_f32_16x16x32_bf16(x0, bxlA, a00, 0, 0, 0);
            a01 = __builtin_amdgcn_mfma_f32_16x16x32_bf16(x0, bxlB, a01, 0, 0, 0);
        }

        // (2) issue next-step x load (lands at loop end)
        uintx4 xn0;
        xn0 = *(const uintx4*)&xr0[(size_t)((t + 1) & (S_ - 1)) * I_ + xkb + q * 8];

        // (3) TUNED DELAY: let all producers' publish stores land at MALL
        //     before the first (and ideally only) bulk sweep samples it.
        burn(DELAY_BURN);

        // (4) issue ALL 16 h-loads (speculative read = arrival detector)
        uintx4 g[16];
#pragma unroll
        for (int ks = 0; ks < 16; ++ks)
            LDG0(g[ks], cb + ks * 512);

        // (5) 4-stage split-wait; group validation (1 ballot / 4 chunks)
        unsigned rem = 0;

        asm volatile("s_waitcnt vmcnt(12)" ::: "memory");
        __builtin_amdgcn_sched_barrier(0);
        {
            unsigned o = 0;
#pragma unroll
            for (int ks = 0; ks < 4; ++ks) o |= g[ks].x | g[ks].y | g[ks].z | g[ks].w;
            if (__ballot((o & SENTMASK) != 0u) == 0ull) {
#pragma unroll
                for (int ks = 0; ks < 4; ++ks)
                    mfma_chunk(a00, a01, g[ks], whA[ks], wlA[ks], whB[ks], wlB[ks]);
            } else rem |= 0x000Fu;
        }

        asm volatile("s_waitcnt vmcnt(8)" ::: "memory");
        __builtin_amdgcn_sched_barrier(0);
        {
            unsigned o = 0;
#pragma unroll
            for (int ks = 4; ks < 8; ++ks) o |= g[ks].x | g[ks].y | g[ks].z | g[ks].w;
            if (__ballot((o & SENTMASK) != 0u) == 0ull) {
#pragma unroll
                for (int ks = 4; ks < 8; ++ks)
                    mfma_chunk(a00, a01, g[ks], whA[ks], wlA[ks], whB[ks], wlB[ks]);
            } else rem |= 0x00F0u;
        }

        asm volatile("s_waitcnt vmcnt(4)" ::: "memory");
        __builtin_amdgcn_sched_barrier(0);
        {
            unsigned o = 0;
#pragma unroll
            for (int ks = 8; ks < 12; ++ks) o |= g[ks].x | g[ks].y | g[ks].z | g[ks].w;
            if (__ballot((o & SENTMASK) != 0u) == 0ull) {
#pragma unroll
                for (int ks = 8; ks < 12; ++ks)
                    mfma_chunk(a00, a01, g[ks], whA[ks], wlA[ks], whB[ks], wlB[ks]);
            } else rem |= 0x0F00u;
        }

        asm volatile("s_waitcnt vmcnt(0)" ::: "memory");
        __builtin_amdgcn_sched_barrier(0);
        {
            unsigned o = 0;
#pragma unroll
            for (int ks = 12; ks < 16; ++ks) o |= g[ks].x | g[ks].y | g[ks].z | g[ks].w;
            if (__ballot((o & SENTMASK) != 0u) == 0ull) {
#pragma unroll
                for (int ks = 12; ks < 16; ++ks)
                    mfma_chunk(a00, a01, g[ks], whA[ks], wlA[ks], whB[ks], wlB[ks]);
            } else rem |= 0xF000u;
        }

        // (5c) retry loop — rare straggler backstop (authoritative,
        //      per-chunk validation)
        while (rem) {
#pragma unroll
            for (int ks = 0; ks < 16; ++ks) if (rem & (1u << ks))
                LDG0(g[ks], cb + ks * 512);
            burn(48);
            asm volatile("s_waitcnt vmcnt(0)" ::: "memory");
            __builtin_amdgcn_sched_barrier(0);
            unsigned nv = 0;
#pragma unroll
            for (int ks = 0; ks < 16; ++ks) if (rem & (1u << ks)) {
                unsigned o = g[ks].x | g[ks].y | g[ks].z | g[ks].w;
                if (__ballot((o & SENTMASK) != 0u) == 0ull) nv |= 1u << ks;
            }
            nv = __builtin_amdgcn_readfirstlane(nv);
#pragma unroll
            for (int ks = 0; ks < 16; ++ks) if (nv & (1u << ks))
                mfma_chunk(a00, a01, g[ks], whA[ks], wlA[ks], whB[ks], wlB[ks]);
            rem &= ~nv;
        }

        // (6) wave partials -> LDS (buffer t&1); 16 rows x 32 cols
        float* sr = sRed[t & 1];
#pragma unroll
        for (int r = 0; r < 4; ++r) {
            sr[(w * 16 + q * 4 + r) * RSTR + nn]      = a00[r];
            sr[(w * 16 + q * 4 + r) * RSTR + 16 + nn] = a01[r];
        }
        __syncthreads();   // sRed ready (also isolates t vs t+2 buffer reuse)

        // (7) reduce 4 waves, +bih, tanh, pack, sc1 store into publish
        //     layout. No drain, no flag — consumers validate the data.
        {
            floatx2 s = *(const floatx2*)&sr[(0 * 16 + m) * RSTR + n0];
            s += *(const floatx2*)&sr[(1 * 16 + m) * RSTR + n0];
            s += *(const floatx2*)&sr[(2 * 16 + m) * RSTR + n0];
            s += *(const floatx2*)&sr[(3 * 16 + m) * RSTR + n0];
            unsigned short u0 = f2bf(fast_tanh(s[0] + sBih[n0 + 0]));
            unsigned short u1 = f2bf(fast_tanh(s[1] + sBih[n0 + 1]));
            unsigned pk = (unsigned)u0 | ((unsigned)u1 << 16);
            unsigned short* dst = hs + (size_t)(t + 1) * SLAB + pub_off;
            asm volatile("global_store_dword %0, %1, off sc1"
                         :: "v"(dst), "v"(pk) : "memory");
        }

        asm volatile("" : "+v"(xn0));   // land x prefetch here
        xc0 = xn0;
    }
}

// ---- output projection: out[b,t,o] = hs[t+1][b,:] . Who[o,:] + bho ------
// hflat points at slab 1; slabs are in PUBLISH layout (see k_rnn header).
__global__ __launch_bounds__(NTHREADS) void k_out(
    const unsigned short* __restrict__ hflat, const unsigned short* __restrict__ who,
    const float* __restrict__ bho, float* __restrict__ out)
{
    const int tid = threadIdx.x;
    const int w = tid >> 6, lane = tid & 63, q = lane >> 4, nn = lane & 15;
    const int r0 = ((int)blockIdx.x * 4 + w) * 16;   // flat row = t*64+b
    const int t  = r0 >> 6;
    const int qt = (r0 >> 4) & 3;
    const unsigned short* const abase =
        hflat + (size_t)t * SLAB + (size_t)qt * QTR_ + (size_t)lane * 8;
    floatx4 acc[8];
#pragma unroll
    for (int i = 0; i < 8; ++i) acc[i] = floatx4{0.f, 0.f, 0.f, 0.f};
    for (int ks = 0; ks < 64; ++ks) {
        const int kk = ks * 32 + q * 8;
        bf16x8 a = *(const bf16x8*)(abase + ks * 512);
#pragma unroll
        for (int nt = 0; nt < 8; ++nt) {
            bf16x8 b = *(const bf16x8*)&who[(size_t)(nt * 16 + nn) * H_ + kk];
            acc[nt] = __builtin_amdgcn_mfma_f32_16x16x32_bf16(a, b, acc[nt], 0, 0, 0);
        }
    }
#pragma unroll
    for (int nt = 0; nt < 8; ++nt) {
#pragma unroll
        for (int r = 0; r < 4; ++r) {
            int rr = r0 + q * 4 + r;
            int tt = rr >> 6, b = rr & 63;
            int o = nt * 16 + nn;
            out[(size_t)b * (S_ * O_) + (size_t)tt * O_ + o] = acc[nt][r] + bho[o];
        }
    }
}

// ---- host ----------------------------------------------------------------
extern "C" void kernel_launch(void* const* d_in, const int* in_sizes, int n_in,
                              void* d_out, int out_size, void* d_ws, size_t ws_size,
                              hipStream_t stream) {
    const float* x    = (const float*)d_in[0];
    const float* Wih  = (const float*)d_in[1];
    const float* bih  = (const float*)d_in[2];
    const float* Whh  = (const float*)d_in[3];
    const float* Who  = (const float*)d_in[4];
    const float* bho  = (const float*)d_in[5];
    const float* mask = (const float*)d_in[6];
    float* out = (float*)d_out;

    char* ws = (char*)d_ws;
    constexpr size_t HS_OFF   = 0;
    constexpr size_t HS_BYTES = (size_t)(S_ + 1) * SLAB * 2;
    constexpr size_t WHI_OFF  = HS_OFF + HS_BYTES;
    constexpr size_t WLO_OFF  = WHI_OFF + (size_t)H_ * H_ * 2;
    constexpr size_t XBF_OFF  = WLO_OFF + (size_t)H_ * H_ * 2;
    constexpr size_t WIHH_OFF = XBF_OFF + (size_t)B_ * S_ * I_ * 2;
    constexpr size_t WIHL_OFF = WIHH_OFF + (size_t)H_ * I_ * 2;
    constexpr size_t WHO_OFF  = WIHL_OFF + (size_t)H_ * I_ * 2;
    constexpr size_t WS_NEED  = WHO_OFF + (size_t)O_ * H_ * 2;
    if (ws_size < WS_NEED) return;

    unsigned short* hs    = (unsigned short*)(ws + HS_OFF);
    unsigned short* whi   = (unsigned short*)(ws + WHI_OFF);
    unsigned short* wlo   = (unsigned short*)(ws + WLO_OFF);
    unsigned short* xbf   = (unsigned short*)(ws + XBF_OFF);
    unsigned short* wihh  = (unsigned short*)(ws + WIHH_OFF);
    unsigned short* wihl  = (unsigned short*)(ws + WIHL_OFF);
    unsigned short* whobf = (unsigned short*)(ws + WHO_OFF);

    hipMemsetAsync(hs, 0, (size_t)SLAB * 2, stream);      // h(0) = 0
    // slabs 1..512 := sentinel (bit14 set) — data-arrival detector
    k_sent<<<2048, 256, 0, stream>>>((uintx4*)(hs + SLAB),
                                     (int)((size_t)S_ * SLAB / 8));

    k_wsplit<<<1024, 256, 0, stream>>>(Whh, mask, whi, wlo, H_ * H_);
    k_split <<<256, 256, 0, stream>>>(Wih, wihh, wihl, H_ * I_);
    k_cast  <<<256, 256, 0, stream>>>(Who, whobf, O_ * H_);
    k_cast  <<<1024, 256, 0, stream>>>(x, xbf, B_ * S_ * I_);

    k_rnn<<<NWG, NTHREADS, 0, stream>>>(whi, wlo, wihh, wihl, xbf, bih, hs);
    k_out<<<512, NTHREADS, 0, stream>>>(hs + SLAB, whobf, bho, out);
}

// Round 17
// 1557.035 us; speedup vs baseline: 1.0505x; 1.0505x over previous
//
#include <hip/hip_runtime.h>
#include <stdint.h>
#include <math.h>

#define B_ 64
#define S_ 512
#define I_ 128
#define H_ 2048
#define O_ 128
#define NWG 256            /* 4 quarters x 64 WGs; 16 rows x 32 cols each */
#define COLS 32
#define NTHREADS 256
#define SLAB (B_ * H_)      /* 131072 elements per h snapshot */
#define QTR_ 32768          /* elements per quarter-slab (16 rows x 2048) */
#define RSTR 36             /* sRed row stride in floats (32 + 4 pad) */
#define SENTW 0x7FC07FC0u   /* qNaN|qNaN — tanh output always has bit14=0 */
#define SENTMASK 0x40004000u
#define DELAY_BURN 144      /* ~580cy: VALIDATED optimum (r26 tripwire:
                               104 -> FETCH 567->595MB + dur +58us) */

typedef __attribute__((ext_vector_type(8))) __bf16 bf16x8;
typedef __attribute__((ext_vector_type(4))) float floatx4;
typedef __attribute__((ext_vector_type(2))) float floatx2;
typedef __attribute__((ext_vector_type(4))) unsigned int uintx4;

__device__ __forceinline__ unsigned short f2bf(float f) {
    unsigned u = __float_as_uint(f);
    unsigned r = u + 0x7fffu + ((u >> 16) & 1u);   // RNE
    return (unsigned short)(r >> 16);
}
__device__ __forceinline__ float bf2f(unsigned short h) {
    return __uint_as_float(((unsigned)h) << 16);
}
// tanh(x) = 1 - 2/(e^{2x}+1); err ~1e-6 << bf16 noise.
__device__ __forceinline__ float fast_tanh(float x) {
    float e = __expf(2.0f * x);
    return 1.0f - 2.0f * __builtin_amdgcn_rcpf(e + 1.0f);
}

// VALU work overlapping in-flight VMEM / absorbing publish flight.
__device__ __forceinline__ void burn(int n) {
    float a = 1.0f, b = 1.0f;
    const float c = 1.0000001f, d = 0.9999999f;
    for (int i = 0; i < n; ++i)
        asm volatile("v_fmac_f32 %0, %2, %2\n\tv_fmac_f32 %1, %3, %3"
                     : "+v"(a), "+v"(b) : "v"(c), "v"(d));
}

// sc0 sc1 b128 load (bypass L1/L2 -> MALL truth). r19 lesson: NO cached
// h loads — a pre-arrival line cached in L2 serves stale sentinel forever.
// r22 lesson: NO probes — the speculative data read IS the detector.
#define LDG0(dst, addr) \
    asm volatile("global_load_dwordx4 %0, %1, off sc0 sc1" \
                 : "=v"(dst) : "v"(addr))

// one chunk's 4 MFMAs (hi+lo x two 16-col tiles)
__device__ __forceinline__ void mfma_chunk(
    floatx4& a00, floatx4& a01, const uintx4 gk,
    const uintx4 whAk, const uintx4 wlAk,
    const uintx4 whBk, const uintx4 wlBk)
{
    const bf16x8 h0 = __builtin_bit_cast(bf16x8, gk);
    const bf16x8 hA = __builtin_bit_cast(bf16x8, whAk);
    const bf16x8 lA = __builtin_bit_cast(bf16x8, wlAk);
    const bf16x8 hB = __builtin_bit_cast(bf16x8, whBk);
    const bf16x8 lB = __builtin_bit_cast(bf16x8, wlBk);
    a00 = __builtin_amdgcn_mfma_f32_16x16x32_bf16(h0, hA, a00, 0, 0, 0);
    a01 = __builtin_amdgcn_mfma_f32_16x16x32_bf16(h0, hB, a01, 0, 0, 0);
    a00 = __builtin_amdgcn_mfma_f32_16x16x32_bf16(h0, lA, a00, 0, 0, 0);
    a01 = __builtin_amdgcn_mfma_f32_16x16x32_bf16(h0, lB, a01, 0, 0, 0);
}

// ---- prep kernels -------------------------------------------------------
__global__ void k_wsplit(const float* __restrict__ whh, const float* __restrict__ mask,
                         unsigned short* __restrict__ hi, unsigned short* __restrict__ lo, int n) {
    int i = blockIdx.x * blockDim.x + threadIdx.x;
    int stride = gridDim.x * blockDim.x;
    for (; i < n; i += stride) {
        float w = whh[i] * mask[i];
        unsigned short h = f2bf(w);
        hi[i] = h;
        lo[i] = f2bf(w - bf2f(h));
    }
}
__global__ void k_split(const float* __restrict__ src,
                        unsigned short* __restrict__ hi, unsigned short* __restrict__ lo, int n) {
    int i = blockIdx.x * blockDim.x + threadIdx.x;
    int stride = gridDim.x * blockDim.x;
    for (; i < n; i += stride) {
        float w = src[i];
        unsigned short h = f2bf(w);
        hi[i] = h;
        lo[i] = f2bf(w - bf2f(h));
    }
}
__global__ void k_cast(const float* __restrict__ src, unsigned short* __restrict__ dst, int n) {
    int i = blockIdx.x * blockDim.x + threadIdx.x;
    int stride = gridDim.x * blockDim.x;
    for (; i < n; i += stride) dst[i] = f2bf(src[i]);
}
// fill hs slabs 1..512 with sentinel (sc1 write-through: no dirty copies)
__global__ void k_sent(uintx4* __restrict__ p, int n4) {
    int i = blockIdx.x * blockDim.x + threadIdx.x;
    int stride = gridDim.x * blockDim.x;
    uintx4 s = {SENTW, SENTW, SENTW, SENTW};
    for (; i < n4; i += stride)
        asm volatile("global_store_dwordx4 %0, %1, off sc1"
                     :: "v"(p + i), "v"(s) : "memory");
}

// ---- persistent recurrence kernel --------------------------------------
// Round-27: REVERT TO r25 (the verified session best, k_rnn 1398us).
//  r26's discriminating experiment resolved: DELAY_BURN 104 inflated
//  FETCH (567->595MB, retries returned) and regressed 58us. 144 is the
//  validated optimum. Final structure:
//   - 4 quarters x 64 WGs (COLS=32): communication-optimal broadcast
//     (16 MB/step) at full chip, fan-in 1 producer per chunk;
//   - coalesced publish layout (lane order == address order);
//   - sentinel dataflow: speculative sc0sc1 reads ARE the arrival
//     detector; tuned pre-issue delay kills the stale first sweep;
//   - 4-stage split-wait (vmcnt 12/8/4/0) + group validation (1 ballot
//     per 4 chunks); per-chunk sc0sc1 retry backstop (authoritative);
//   - W resident in VGPRs (laundered opaque), x prefetched 1 step ahead.
//  Step ~2.0k effective cy: delay 580 + RT residual 200 + consume 550
//  (330 MFMA) + reduce/epilogue 400 + loop 250; concurrently ~5.9 TB/s
//  MALL broadcast service. Serial-chain + fabric floor reached.
__global__ __attribute__((amdgpu_flat_work_group_size(NTHREADS, NTHREADS),
                          amdgpu_waves_per_eu(1, 1))) void k_rnn(
    const unsigned short* __restrict__ whi, const unsigned short* __restrict__ wlo,
    const unsigned short* __restrict__ wihh, const unsigned short* __restrict__ wihl,
    const unsigned short* __restrict__ xbf, const float* __restrict__ bih,
    unsigned short* hs)
{
    __shared__ float sRed[2][4 * 16 * RSTR];
    __shared__ float sBih[COLS];

    const int tid   = threadIdx.x;
    const int wg    = blockIdx.x;
    const int qt    = wg >> 6;          // quarter: rows qt*16..qt*16+15
    const int wgl   = wg & 63;
    const int j0    = wgl * COLS;
    const int rbase = qt * 16;
    const int w     = tid >> 6;
    const int lane  = tid & 63;
    const int q     = lane >> 4;
    const int nn    = lane & 15;
    const int kb    = w * 512;   // this wave's k range in H
    const int xkb   = w * 32;    // this wave's k range in I

    if (tid < COLS) sBih[tid] = bih[j0 + tid];

    // W fragments — loaded once, laundered opaque (stay resident).
    uintx4 whA[16], wlA[16], whB[16], wlB[16];
    uintx4 bxhA_u, bxlA_u, bxhB_u, bxlB_u;
    {
        const size_t wrowA = (size_t)(j0 + nn)      * H_ + (size_t)(kb + q * 8);
        const size_t wrowB = (size_t)(j0 + 16 + nn) * H_ + (size_t)(kb + q * 8);
#pragma unroll
        for (int ks = 0; ks < 16; ++ks) {
            whA[ks] = *(const uintx4*)&whi[wrowA + ks * 32];
            wlA[ks] = *(const uintx4*)&wlo[wrowA + ks * 32];
            whB[ks] = *(const uintx4*)&whi[wrowB + ks * 32];
            wlB[ks] = *(const uintx4*)&wlo[wrowB + ks * 32];
        }
        const size_t xrowA = (size_t)(j0 + nn)      * I_ + (size_t)(xkb + q * 8);
        const size_t xrowB = (size_t)(j0 + 16 + nn) * I_ + (size_t)(xkb + q * 8);
        bxhA_u = *(const uintx4*)&wihh[xrowA];
        bxlA_u = *(const uintx4*)&wihl[xrowA];
        bxhB_u = *(const uintx4*)&wihh[xrowB];
        bxlB_u = *(const uintx4*)&wihl[xrowB];
#pragma unroll
        for (int ks = 0; ks < 16; ++ks)
            asm volatile("" : "+v"(whA[ks]), "+v"(wlA[ks]),
                              "+v"(whB[ks]), "+v"(wlB[ks]));
        asm volatile("" : "+v"(bxhA_u), "+v"(bxlA_u),
                          "+v"(bxhB_u), "+v"(bxlB_u));
    }
    const bf16x8 bxhA = __builtin_bit_cast(bf16x8, bxhA_u);
    const bf16x8 bxlA = __builtin_bit_cast(bf16x8, bxlA_u);
    const bf16x8 bxhB = __builtin_bit_cast(bf16x8, bxhB_u);
    const bf16x8 bxlB = __builtin_bit_cast(bf16x8, bxlB_u);

    // consumer base: wave w reads blocks w*16+ks of quarter qt
    const unsigned short* const cwbase =
        hs + (size_t)qt * QTR_ + (size_t)w * 8192 + (size_t)lane * 8;

    // producer publish offset: block wgl of quarter qt; 256 threads,
    // row m=tid>>4 (0..15), col pair n0=(tid&15)*2.
    const int m  = tid >> 4;
    const int n0 = (tid & 15) * 2;
    const size_t pub_off =
        (size_t)qt * QTR_ + (size_t)wgl * 512 +
        (size_t)(((n0 >> 3) & 3) * 16 + m) * 8 + (size_t)(n0 & 7);

    // x row for this WG's single 16-row tile
    const unsigned short* const xr0 = xbf + (size_t)(rbase + nn) * (S_ * I_);

    // prologue: prefetch x operand for t=0
    uintx4 xc0;
    {
        xc0 = *(const uintx4*)&xr0[(size_t)xkb + q * 8];
        asm volatile("" : "+v"(xc0));
    }

#pragma unroll 1
    for (int t = 0; t < S_; ++t) {
        const unsigned short* cb = cwbase + (size_t)t * SLAB;

        // (1) register-only x-projection (free delay, no memory)
        floatx4 a00 = {0.f, 0.f, 0.f, 0.f}, a01 = a00;
        {
            bf16x8 x0 = __builtin_bit_cast(bf16x8, xc0);
            a00 = __builtin_amdgcn_mfma_f32_16x16x32_bf16(x0, bxhA, a00, 0, 0, 0);
            a01 = __builtin_amdgcn_mfma_f32_16x16x32_bf16(x0, bxhB, a01, 0, 0, 0);
            a00 = __builtin_amdgcn_mfma_f32_16x16x32_bf16(x0, bxlA, a00, 0, 0, 0);
            a01 = __builtin_amdgcn_mfma_f32_16x16x32_bf16(x0, bxlB, a01, 0, 0, 0);
        }

        // (2) issue next-step x load (lands at loop end)
        uintx4 xn0;
        xn0 = *(const uintx4*)&xr0[(size_t)((t + 1) & (S_ - 1)) * I_ + xkb + q * 8];

        // (3) TUNED DELAY: let all producers' publish stores land at MALL
        //     before the first (and ideally only) bulk sweep samples it.
        burn(DELAY_BURN);

        // (4) issue ALL 16 h-loads (speculative read = arrival detector)
        uintx4 g[16];
#pragma unroll
        for (int ks = 0; ks < 16; ++ks)
            LDG0(g[ks], cb + ks * 512);

        burn(24);   // small cover; vmcnt(12) does the rest

        // (5) 4-stage split-wait; group validation (1 ballot / 4 chunks)
        unsigned rem = 0;

        asm volatile("s_waitcnt vmcnt(12)" ::: "memory");
        __builtin_amdgcn_sched_barrier(0);
        {
            unsigned o = 0;
#pragma unroll
            for (int ks = 0; ks < 4; ++ks) o |= g[ks].x | g[ks].y | g[ks].z | g[ks].w;
            if (__ballot((o & SENTMASK) != 0u) == 0ull) {
#pragma unroll
                for (int ks = 0; ks < 4; ++ks)
                    mfma_chunk(a00, a01, g[ks], whA[ks], wlA[ks], whB[ks], wlB[ks]);
            } else rem |= 0x000Fu;
        }

        asm volatile("s_waitcnt vmcnt(8)" ::: "memory");
        __builtin_amdgcn_sched_barrier(0);
        {
            unsigned o = 0;
#pragma unroll
            for (int ks = 4; ks < 8; ++ks) o |= g[ks].x | g[ks].y | g[ks].z | g[ks].w;
            if (__ballot((o & SENTMASK) != 0u) == 0ull) {
#pragma unroll
                for (int ks = 4; ks < 8; ++ks)
                    mfma_chunk(a00, a01, g[ks], whA[ks], wlA[ks], whB[ks], wlB[ks]);
            } else rem |= 0x00F0u;
        }

        asm volatile("s_waitcnt vmcnt(4)" ::: "memory");
        __builtin_amdgcn_sched_barrier(0);
        {
            unsigned o = 0;
#pragma unroll
            for (int ks = 8; ks < 12; ++ks) o |= g[ks].x | g[ks].y | g[ks].z | g[ks].w;
            if (__ballot((o & SENTMASK) != 0u) == 0ull) {
#pragma unroll
                for (int ks = 8; ks < 12; ++ks)
                    mfma_chunk(a00, a01, g[ks], whA[ks], wlA[ks], whB[ks], wlB[ks]);
            } else rem |= 0x0F00u;
        }

        asm volatile("s_waitcnt vmcnt(0)" ::: "memory");
        __builtin_amdgcn_sched_barrier(0);
        {
            unsigned o = 0;
#pragma unroll
            for (int ks = 12; ks < 16; ++ks) o |= g[ks].x | g[ks].y | g[ks].z | g[ks].w;
            if (__ballot((o & SENTMASK) != 0u) == 0ull) {
#pragma unroll
                for (int ks = 12; ks < 16; ++ks)
                    mfma_chunk(a00, a01, g[ks], whA[ks], wlA[ks], whB[ks], wlB[ks]);
            } else rem |= 0xF000u;
        }

        // (5c) retry loop — rare straggler backstop (authoritative,
        //      per-chunk validation)
        while (rem) {
#pragma unroll
            for (int ks = 0; ks < 16; ++ks) if (rem & (1u << ks))
                LDG0(g[ks], cb + ks * 512);
            burn(48);
            asm volatile("s_waitcnt vmcnt(0)" ::: "memory");
            __builtin_amdgcn_sched_barrier(0);
            unsigned nv = 0;
#pragma unroll
            for (int ks = 0; ks < 16; ++ks) if (rem & (1u << ks)) {
                unsigned o = g[ks].x | g[ks].y | g[ks].z | g[ks].w;
                if (__ballot((o & SENTMASK) != 0u) == 0ull) nv |= 1u << ks;
            }
            nv = __builtin_amdgcn_readfirstlane(nv);
#pragma unroll
            for (int ks = 0; ks < 16; ++ks) if (nv & (1u << ks))
                mfma_chunk(a00, a01, g[ks], whA[ks], wlA[ks], whB[ks], wlB[ks]);
            rem &= ~nv;
        }

        // (6) wave partials -> LDS (buffer t&1); 16 rows x 32 cols
        float* sr = sRed[t & 1];
#pragma unroll
        for (int r = 0; r < 4; ++r) {
            sr[(w * 16 + q * 4 + r) * RSTR + nn]      = a00[r];
            sr[(w * 16 + q * 4 + r) * RSTR + 16 + nn] = a01[r];
        }
        __syncthreads();   // sRed ready (also isolates t vs t+2 buffer reuse)

        // (7) reduce 4 waves, +bih, tanh, pack, sc1 store into publish
        //     layout. No drain, no flag — consumers validate the data.
        {
            floatx2 s = *(const floatx2*)&sr[(0 * 16 + m) * RSTR + n0];
            s += *(const floatx2*)&sr[(1 * 16 + m) * RSTR + n0];
            s += *(const floatx2*)&sr[(2 * 16 + m) * RSTR + n0];
            s += *(const floatx2*)&sr[(3 * 16 + m) * RSTR + n0];
            unsigned short u0 = f2bf(fast_tanh(s[0] + sBih[n0 + 0]));
            unsigned short u1 = f2bf(fast_tanh(s[1] + sBih[n0 + 1]));
            unsigned pk = (unsigned)u0 | ((unsigned)u1 << 16);
            unsigned short* dst = hs + (size_t)(t + 1) * SLAB + pub_off;
            asm volatile("global_store_dword %0, %1, off sc1"
                         :: "v"(dst), "v"(pk) : "memory");
        }

        asm volatile("" : "+v"(xn0));   // land x prefetch here
        xc0 = xn0;
    }
}

// ---- output projection: out[b,t,o] = hs[t+1][b,:] . Who[o,:] + bho ------
// hflat points at slab 1; slabs are in PUBLISH layout (see k_rnn header).
__global__ __launch_bounds__(NTHREADS) void k_out(
    const unsigned short* __restrict__ hflat, const unsigned short* __restrict__ who,
    const float* __restrict__ bho, float* __restrict__ out)
{
    const int tid = threadIdx.x;
    const int w = tid >> 6, lane = tid & 63, q = lane >> 4, nn = lane & 15;
    const int r0 = ((int)blockIdx.x * 4 + w) * 16;   // flat row = t*64+b
    const int t  = r0 >> 6;
    const int qt = (r0 >> 4) & 3;
    const unsigned short* const abase =
        hflat + (size_t)t * SLAB + (size_t)qt * QTR_ + (size_t)lane * 8;
    floatx4 acc[8];
#pragma unroll
    for (int i = 0; i < 8; ++i) acc[i] = floatx4{0.f, 0.f, 0.f, 0.f};
    for (int ks = 0; ks < 64; ++ks) {
        const int kk = ks * 32 + q * 8;
        bf16x8 a = *(const bf16x8*)(abase + ks * 512);
#pragma unroll
        for (int nt = 0; nt < 8; ++nt) {
            bf16x8 b = *(const bf16x8*)&who[(size_t)(nt * 16 + nn) * H_ + kk];
            acc[nt] = __builtin_amdgcn_mfma_f32_16x16x32_bf16(a, b, acc[nt], 0, 0, 0);
        }
    }
#pragma unroll
    for (int nt = 0; nt < 8; ++nt) {
#pragma unroll
        for (int r = 0; r < 4; ++r) {
            int rr = r0 + q * 4 + r;
            int tt = rr >> 6, b = rr & 63;
            int o = nt * 16 + nn;
            out[(size_t)b * (S_ * O_) + (size_t)tt * O_ + o] = acc[nt][r] + bho[o];
        }
    }
}

// ---- host ----------------------------------------------------------------
extern "C" void kernel_launch(void* const* d_in, const int* in_sizes, int n_in,
                              void* d_out, int out_size, void* d_ws, size_t ws_size,
                              hipStream_t stream) {
    const float* x    = (const float*)d_in[0];
    const float* Wih  = (const float*)d_in[1];
    const float* bih  = (const float*)d_in[2];
    const float* Whh  = (const float*)d_in[3];
    const float* Who  = (const float*)d_in[4];
    const float* bho  = (const float*)d_in[5];
    const float* mask = (const float*)d_in[6];
    float* out = (float*)d_out;

    char* ws = (char*)d_ws;
    constexpr size_t HS_OFF   = 0;
    constexpr size_t HS_BYTES = (size_t)(S_ + 1) * SLAB * 2;
    constexpr size_t WHI_OFF  = HS_OFF + HS_BYTES;
    constexpr size_t WLO_OFF  = WHI_OFF + (size_t)H_ * H_ * 2;
    constexpr size_t XBF_OFF  = WLO_OFF + (size_t)H_ * H_ * 2;
    constexpr size_t WIHH_OFF = XBF_OFF + (size_t)B_ * S_ * I_ * 2;
    constexpr size_t WIHL_OFF = WIHH_OFF + (size_t)H_ * I_ * 2;
    constexpr size_t WHO_OFF  = WIHL_OFF + (size_t)H_ * I_ * 2;
    constexpr size_t WS_NEED  = WHO_OFF + (size_t)O_ * H_ * 2;
    if (ws_size < WS_NEED) return;

    unsigned short* hs    = (unsigned short*)(ws + HS_OFF);
    unsigned short* whi   = (unsigned short*)(ws + WHI_OFF);
    unsigned short* wlo   = (unsigned short*)(ws + WLO_OFF);
    unsigned short* xbf   = (unsigned short*)(ws + XBF_OFF);
    unsigned short* wihh  = (unsigned short*)(ws + WIHH_OFF);
    unsigned short* wihl  = (unsigned short*)(ws + WIHL_OFF);
    unsigned short* whobf = (unsigned short*)(ws + WHO_OFF);

    hipMemsetAsync(hs, 0, (size_t)SLAB * 2, stream);      // h(0) = 0
    // slabs 1..512 := sentinel (bit14 set) — data-arrival detector
    k_sent<<<2048, 256, 0, stream>>>((uintx4*)(hs + SLAB),
                                     (int)((size_t)S_ * SLAB / 8));

    k_wsplit<<<1024, 256, 0, stream>>>(Whh, mask, whi, wlo, H_ * H_);
    k_split <<<256, 256, 0, stream>>>(Wih, wihh, wihl, H_ * I_);
    k_cast  <<<256, 256, 0, stream>>>(Who, whobf, O_ * H_);
    k_cast  <<<1024, 256, 0, stream>>>(x, xbf, B_ * S_ * I_);

    k_rnn<<<NWG, NTHREADS, 0, stream>>>(whi, wlo, wihh, wihl, xbf, bih, hs);
    k_out<<<512, NTHREADS, 0, stream>>>(hs + SLAB, whobf, bho, out);
}